// Round 1
// baseline (1248.551 us; speedup 1.0000x reference)
//
#include <hip/hip_runtime.h>

// PINN fused kernel: u, du/dx0, d2u/dx0^2 of tanh-MLP (2->256->256->256->1)
// Forward-mode:
//   layer1: z=x@W1+b1, z'=W1[0,:], z''=0
//   layerL: z=a@W+b, z'=a'@W, z''=a''@W ; a=tanh(z), s=1-a^2,
//           a'=s*z', a''=s*z'' - 2*a*a'*z'
//   out: u=a3@W4+b4, u'=a3'@W4, u''=a3''@W4
//
// Design: TM=16 samples/block, 256 threads (4 waves), per-thread 4m x 4n tile.
// States Av/Ad/Add [256][16] fp32 in LDS (48KB -> 3 blocks/CU).
// k-loop: W row via coalesced global float4 (L1/L2 resident), A frags via
// LDS b128 broadcast (all lanes in a wave read the same 16B -> conflict-free).

#define HID 256
#define TM  16

__global__ __launch_bounds__(256) void pinn_fused(
    const float* __restrict__ x,
    const float* __restrict__ W1, const float* __restrict__ b1,
    const float* __restrict__ W2, const float* __restrict__ b2,
    const float* __restrict__ W3, const float* __restrict__ b3,
    const float* __restrict__ W4, const float* __restrict__ b4,
    float* __restrict__ out, int B)
{
    __shared__ float Av[HID][TM];
    __shared__ float Ad[HID][TM];
    __shared__ float Add[HID][TM];
    __shared__ float psum[12][TM];

    const int tid = threadIdx.x;
    const int s0  = blockIdx.x * TM;

    // ---------- Layer 1 (closed form tangents) ----------
    {
        const int n = tid;                 // one hidden unit per thread
        const float w0 = W1[n];            // W1[0][n]  (= z1' for every sample)
        const float w1 = W1[HID + n];      // W1[1][n]
        const float bb = b1[n];
        #pragma unroll
        for (int m = 0; m < TM; ++m) {
            const float x0 = x[(s0 + m) * 2 + 0];
            const float x1 = x[(s0 + m) * 2 + 1];
            const float z  = fmaf(x0, w0, fmaf(x1, w1, bb));
            const float a  = tanhf(z);
            const float sN = 1.0f - a * a;
            const float ad = sN * w0;                    // a1' = s * z1'
            const float a2 = -2.0f * a * ad * w0;        // a1'' = -2 a a1' z1'
            Av[n][m]  = a;
            Ad[n][m]  = ad;
            Add[n][m] = a2;
        }
    }
    __syncthreads();

    const int m_t = tid >> 6;      // wave id 0..3
    const int n_t = tid & 63;      // lane    0..63
    const int m0  = m_t * 4;
    const int n0  = n_t * 4;

    // ---------- Layers 2 and 3 ----------
    #pragma unroll 1
    for (int layer = 0; layer < 2; ++layer) {
        const float* __restrict__ W    = (layer == 0) ? W2 : W3;
        const float* __restrict__ bvec = (layer == 0) ? b2 : b3;

        float accv[4][4];
        float accd[4][4];
        float acc2[4][4];
        #pragma unroll
        for (int i = 0; i < 4; ++i)
            #pragma unroll
            for (int j = 0; j < 4; ++j) {
                accv[i][j] = 0.0f; accd[i][j] = 0.0f; acc2[i][j] = 0.0f;
            }

        #pragma unroll 4
        for (int k = 0; k < HID; ++k) {
            const float4 w4  = *(const float4*)(W + (size_t)k * HID + n0);
            const float4 av4 = *(const float4*)(&Av[k][m0]);
            const float4 ad4 = *(const float4*)(&Ad[k][m0]);
            const float4 a24 = *(const float4*)(&Add[k][m0]);
            const float* wp  = (const float*)&w4;
            const float* avp = (const float*)&av4;
            const float* adp = (const float*)&ad4;
            const float* a2p = (const float*)&a24;
            #pragma unroll
            for (int i = 0; i < 4; ++i) {
                #pragma unroll
                for (int j = 0; j < 4; ++j) {
                    accv[i][j] = fmaf(avp[i], wp[j], accv[i][j]);
                    accd[i][j] = fmaf(adp[i], wp[j], accd[i][j]);
                    acc2[i][j] = fmaf(a2p[i], wp[j], acc2[i][j]);
                }
            }
        }

        // everyone done reading Av/Ad/Add before we overwrite them
        __syncthreads();

        float bj[4];
        #pragma unroll
        for (int j = 0; j < 4; ++j) bj[j] = bvec[n0 + j];

        float na[4][4], nad[4][4], na2[4][4];
        #pragma unroll
        for (int i = 0; i < 4; ++i) {
            #pragma unroll
            for (int j = 0; j < 4; ++j) {
                const float z   = accv[i][j] + bj[j];
                const float a   = tanhf(z);
                const float sN  = 1.0f - a * a;
                const float zd  = accd[i][j];
                const float zdd = acc2[i][j];
                const float ad  = sN * zd;
                const float a2  = fmaf(sN, zdd, -2.0f * a * ad * zd);
                na[i][j] = a; nad[i][j] = ad; na2[i][j] = a2;
            }
        }

        // transposed write-back: state row index = this layer's n
        #pragma unroll
        for (int j = 0; j < 4; ++j) {
            float4 v, d, d2;
            v.x  = na[0][j];  v.y  = na[1][j];  v.z  = na[2][j];  v.w  = na[3][j];
            d.x  = nad[0][j]; d.y  = nad[1][j]; d.z  = nad[2][j]; d.w  = nad[3][j];
            d2.x = na2[0][j]; d2.y = na2[1][j]; d2.z = na2[2][j]; d2.w = na2[3][j];
            *(float4*)(&Av[n0 + j][m0])  = v;
            *(float4*)(&Ad[n0 + j][m0])  = d;
            *(float4*)(&Add[n0 + j][m0]) = d2;
        }
        __syncthreads();
    }

    // ---------- Output layer: 3 dot products of length 256 per sample ----------
    {
        const int part = tid >> 4;      // 0..15
        const int mi   = tid & 15;
        if (part < 12) {
            const int p = part % 3;     // path
            const int c = part / 3;     // k-chunk 0..3 (64 each)
            const float* src = (p == 0) ? &Av[0][0] : (p == 1) ? &Ad[0][0] : &Add[0][0];
            float s = 0.0f;
            const int k0 = c * 64;
            #pragma unroll 8
            for (int k = k0; k < k0 + 64; ++k)
                s = fmaf(src[k * TM + mi], W4[k], s);
            psum[part][mi] = s;
        }
    }
    __syncthreads();
    if (tid < 48) {
        const int p  = tid >> 4;        // 0..2 : u, du, d2u
        const int mi = tid & 15;
        float v = psum[p][mi] + psum[3 + p][mi] + psum[6 + p][mi] + psum[9 + p][mi];
        if (p == 0) v += b4[0];
        out[(size_t)p * B + s0 + mi] = v;
    }
}

extern "C" void kernel_launch(void* const* d_in, const int* in_sizes, int n_in,
                              void* d_out, int out_size, void* d_ws, size_t ws_size,
                              hipStream_t stream) {
    const float* x  = (const float*)d_in[0];
    const float* W1 = (const float*)d_in[1];
    const float* b1 = (const float*)d_in[2];
    const float* W2 = (const float*)d_in[3];
    const float* b2 = (const float*)d_in[4];
    const float* W3 = (const float*)d_in[5];
    const float* b3 = (const float*)d_in[6];
    const float* W4 = (const float*)d_in[7];
    const float* b4 = (const float*)d_in[8];
    float* out = (float*)d_out;

    const int B = in_sizes[0] / 2;      // x is (B, 2)
    const int grid = B / TM;            // 131072/16 = 8192, exact

    pinn_fused<<<grid, 256, 0, stream>>>(x, W1, b1, W2, b2, W3, b3, W4, b4, out, B);
}

// Round 2
// 377.367 us; speedup vs baseline: 3.3086x; 3.3086x over previous
//
#include <hip/hip_runtime.h>

// PINN fused: u, du/dx0, d2u/dx0^2 of tanh-MLP (2->256->256->256->1), fp32 in/out.
// Round 2: fp16 3-term-split MFMA (ahi*whi + ahi*wlo + alo*whi), fp32 accum.
//   - prep_w packs W2/W3 into MFMA B-fragment order, hi/lo fp16, in d_ws (512KB)
//   - main kernel: 16 samples/block, 4 waves x 64-col strips,
//     v_mfma_f32_16x16x32_f16, A-streams staged in LDS as hi/lo fp16 [m][k].

#define HID 256
#define TM  16
#define LDK 264   // padded LDS row stride in f16 elems (+16B): uniform bank spread

typedef _Float16 half8 __attribute__((ext_vector_type(8)));
typedef float    f32x4 __attribute__((ext_vector_type(4)));

// Pack W (fp32 [256][256], row=k, col=n) into fragment order:
// pack[(((nt*8 + kc)*64) + lane)*8 + j] = W[kc*32 + (lane>>4)*8 + j][nt*16 + (lane&15)]
// hi = fp16(w), lo = fp16(w - hi). Layout in ws (f16 elems):
//   W2hi @ 0, W2lo @ 65536, W3hi @ 131072, W3lo @ 196608   (512KB total)
__global__ __launch_bounds__(256) void prep_w(const float* __restrict__ W2,
                                              const float* __restrict__ W3,
                                              _Float16* __restrict__ wsf) {
    const int t = blockIdx.x * 256 + threadIdx.x;          // 0..16383
    const float* __restrict__ W = (t >> 13) ? W3 : W2;
    _Float16* hi = wsf + (size_t)(t >> 13) * 131072;
    _Float16* lo = hi + 65536;
    const int r    = t & 8191;
    const int nt   = r >> 9;
    const int kc   = (r >> 6) & 7;
    const int lane = r & 63;
    const int row  = kc * 32 + ((lane >> 4) << 3);
    const int col  = nt * 16 + (lane & 15);
    half8 vh, vl;
    #pragma unroll
    for (int j = 0; j < 8; ++j) {
        const float w = W[(size_t)(row + j) * HID + col];
        const _Float16 h = (_Float16)w;
        vh[j] = h;
        vl[j] = (_Float16)(w - (float)h);
    }
    *(half8*)&hi[(size_t)r * 8] = vh;
    *(half8*)&lo[(size_t)r * 8] = vl;
}

__global__ __launch_bounds__(256, 3) void pinn_mfma(
    const float* __restrict__ x,
    const float* __restrict__ W1, const float* __restrict__ b1,
    const float* __restrict__ b2, const float* __restrict__ b3,
    const float* __restrict__ W4, const float* __restrict__ b4,
    const _Float16* __restrict__ wsf,
    float* __restrict__ out, int B)
{
    __shared__ __align__(16) _Float16 Ahi[3][TM][LDK];
    __shared__ __align__(16) _Float16 Alo[3][TM][LDK];
    __shared__ float psum[12][TM];

    const int tid  = threadIdx.x;
    const int s0   = blockIdx.x * TM;
    const int lane = tid & 63;
    const int wave = tid >> 6;

    // ---------- Layer 1 (closed-form tangents), split-store to LDS ----------
    {
        const int n = tid;
        const float w0 = W1[n];
        const float w1 = W1[HID + n];
        const float bb = b1[n];
        #pragma unroll
        for (int m = 0; m < TM; ++m) {
            const float x0 = x[(s0 + m) * 2 + 0];
            const float x1 = x[(s0 + m) * 2 + 1];
            const float z  = fmaf(x0, w0, fmaf(x1, w1, bb));
            const float a  = tanhf(z);
            const float sN = 1.0f - a * a;
            const float ad  = sN * w0;
            const float add = -2.0f * a * ad * w0;
            _Float16 h;
            h = (_Float16)a;   Ahi[0][m][n] = h; Alo[0][m][n] = (_Float16)(a   - (float)h);
            h = (_Float16)ad;  Ahi[1][m][n] = h; Alo[1][m][n] = (_Float16)(ad  - (float)h);
            h = (_Float16)add; Ahi[2][m][n] = h; Alo[2][m][n] = (_Float16)(add - (float)h);
        }
    }
    __syncthreads();

    const int ml = lane & 15;            // A-frag m row
    const int kq = (lane >> 4) * 8;      // A/B-frag k offset within 32-chunk

    // ---------- Layers 2 and 3: split-fp16 MFMA ----------
    #pragma unroll 1
    for (int layer = 0; layer < 2; ++layer) {
        const _Float16* __restrict__ Wh = wsf + (size_t)layer * 131072;
        const _Float16* __restrict__ Wl = Wh + 65536;
        const float* __restrict__ bvec  = layer ? b3 : b2;

        f32x4 acc[3][4];
        #pragma unroll
        for (int s = 0; s < 3; ++s)
            #pragma unroll
            for (int nt = 0; nt < 4; ++nt)
                acc[s][nt] = (f32x4){0.f, 0.f, 0.f, 0.f};

        #pragma unroll 1
        for (int kc = 0; kc < 8; ++kc) {
            half8 bh[4], bl[4], ah[3], al[3];
            #pragma unroll
            for (int nt = 0; nt < 4; ++nt) {
                const size_t fi = ((size_t)(((wave * 4 + nt) * 8 + kc) * 64 + lane)) * 8;
                bh[nt] = *(const half8*)&Wh[fi];
                bl[nt] = *(const half8*)&Wl[fi];
            }
            #pragma unroll
            for (int s = 0; s < 3; ++s) {
                ah[s] = *(const half8*)&Ahi[s][ml][kc * 32 + kq];
                al[s] = *(const half8*)&Alo[s][ml][kc * 32 + kq];
            }
            #pragma unroll
            for (int s = 0; s < 3; ++s) {
                #pragma unroll
                for (int nt = 0; nt < 4; ++nt) {
                    acc[s][nt] = __builtin_amdgcn_mfma_f32_16x16x32_f16(ah[s], bh[nt], acc[s][nt], 0, 0, 0);
                    acc[s][nt] = __builtin_amdgcn_mfma_f32_16x16x32_f16(al[s], bh[nt], acc[s][nt], 0, 0, 0);
                    acc[s][nt] = __builtin_amdgcn_mfma_f32_16x16x32_f16(ah[s], bl[nt], acc[s][nt], 0, 0, 0);
                }
            }
        }

        __syncthreads();   // all waves done reading current A before overwrite

        float bn[4];
        #pragma unroll
        for (int nt = 0; nt < 4; ++nt)
            bn[nt] = bvec[wave * 64 + nt * 16 + (lane & 15)];

        // epilogue: D layout row m = (lane>>4)*4 + r, col n = wave*64 + nt*16 + (lane&15)
        #pragma unroll
        for (int nt = 0; nt < 4; ++nt) {
            const int n = wave * 64 + nt * 16 + (lane & 15);
            #pragma unroll
            for (int r = 0; r < 4; ++r) {
                const int m = (lane >> 4) * 4 + r;
                const float z   = acc[0][nt][r] + bn[nt];
                const float a   = tanhf(z);
                const float sN  = 1.0f - a * a;
                const float zd  = acc[1][nt][r];
                const float zdd = acc[2][nt][r];
                const float ad  = sN * zd;
                const float add = fmaf(sN, zdd, -2.0f * a * ad * zd);
                _Float16 h;
                h = (_Float16)a;   Ahi[0][m][n] = h; Alo[0][m][n] = (_Float16)(a   - (float)h);
                h = (_Float16)ad;  Ahi[1][m][n] = h; Alo[1][m][n] = (_Float16)(ad  - (float)h);
                h = (_Float16)add; Ahi[2][m][n] = h; Alo[2][m][n] = (_Float16)(add - (float)h);
            }
        }
        __syncthreads();
    }

    // ---------- Output layer: 3 dot products (K=256) per sample ----------
    {
        const int part = tid >> 4;      // 0..15
        const int mi   = tid & 15;
        if (part < 12) {
            const int p = part % 3;     // path: u, du, d2u
            const int c = part / 3;     // k-chunk of 64
            float ssum = 0.0f;
            #pragma unroll
            for (int kb = 0; kb < 8; ++kb) {
                const int k0 = c * 64 + kb * 8;
                const half8 h = *(const half8*)&Ahi[p][mi][k0];
                const half8 l = *(const half8*)&Alo[p][mi][k0];
                #pragma unroll
                for (int j = 0; j < 8; ++j)
                    ssum = fmaf((float)h[j] + (float)l[j], W4[k0 + j], ssum);
            }
            psum[part][mi] = ssum;
        }
    }
    __syncthreads();
    if (tid < 48) {
        const int p  = tid >> 4;
        const int mi = tid & 15;
        float v = psum[p][mi] + psum[3 + p][mi] + psum[6 + p][mi] + psum[9 + p][mi];
        if (p == 0) v += b4[0];
        out[(size_t)p * B + s0 + mi] = v;
    }
}

extern "C" void kernel_launch(void* const* d_in, const int* in_sizes, int n_in,
                              void* d_out, int out_size, void* d_ws, size_t ws_size,
                              hipStream_t stream) {
    const float* x  = (const float*)d_in[0];
    const float* W1 = (const float*)d_in[1];
    const float* b1 = (const float*)d_in[2];
    const float* W2 = (const float*)d_in[3];
    const float* b2 = (const float*)d_in[4];
    const float* W3 = (const float*)d_in[5];
    const float* b3 = (const float*)d_in[6];
    const float* W4 = (const float*)d_in[7];
    const float* b4 = (const float*)d_in[8];
    float* out = (float*)d_out;

    const int B = in_sizes[0] / 2;      // x is (B, 2)

    prep_w<<<64, 256, 0, stream>>>(W2, W3, (_Float16*)d_ws);
    pinn_mfma<<<B / TM, 256, 0, stream>>>(x, W1, b1, b2, b3, W4, b4,
                                          (const _Float16*)d_ws, out, B);
}

// Round 3
// 330.493 us; speedup vs baseline: 3.7778x; 1.1418x over previous
//
#include <hip/hip_runtime.h>

// PINN fused: u, du/dx0, d2u/dx0^2 of tanh-MLP (2->256->256->256->1), fp32 in/out.
// Round 3: fp16 3-term-split MFMA with SWAPPED operands (A=W^T, B=activations):
//   D rows = hidden units (4 consecutive per acc reg) -> vectorized epilogue stores.
//   Fast tanh via v_exp_f32 + v_rcp_f32. Output dot fused into layer-3 epilogue
//   (register-level, shfl_xor reduction) -- layer-3 never touches LDS.

#define HID 256
#define TM  16
#define LDK 264   // padded LDS row stride in f16 elems

typedef _Float16 half8 __attribute__((ext_vector_type(8)));
typedef _Float16 half4 __attribute__((ext_vector_type(4)));
typedef float    f32x4 __attribute__((ext_vector_type(4)));

__device__ __forceinline__ float fast_tanh(float z) {
    // tanh(z) = 1 - 2/(exp(2z)+1); saturates correctly at +-inf
    const float e = __expf(2.0f * z);
#if __has_builtin(__builtin_amdgcn_rcpf)
    const float r = __builtin_amdgcn_rcpf(e + 1.0f);
#else
    const float r = 1.0f / (e + 1.0f);
#endif
    return fmaf(-2.0f, r, 1.0f);
}

// Pack W2/W3 (fp32 [256][256], row=k, col=n) into MFMA A-fragment order for W^T:
// frag element (tile nt, k-chunk kc, lane, j) = W[kc*32 + (lane>>4)*8 + j][nt*16 + (lane&15)]
// hi = fp16(w), lo = fp16(w - hi).  ws layout (f16): W2hi@0, W2lo@65536, W3hi@131072, W3lo@196608.
__global__ __launch_bounds__(256) void prep_w(const float* __restrict__ W2,
                                              const float* __restrict__ W3,
                                              _Float16* __restrict__ wsf) {
    const int e   = blockIdx.x * 256 + threadIdx.x;   // 0..131071, one per element
    const int mat = e >> 16;
    const int row = (e >> 8) & 255;                   // k
    const int col = e & 255;                          // n
    const float* __restrict__ W = mat ? W3 : W2;
    _Float16* hi = wsf + (size_t)mat * 131072;
    _Float16* lo = hi + 65536;
    const float w = W[row * HID + col];               // coalesced in col
    const _Float16 h = (_Float16)w;
    const int kc   = row >> 5;
    const int lane = ((row >> 3) & 3) * 16 + (col & 15);
    const int j    = row & 7;
    const int nt   = col >> 4;
    const size_t fi = ((size_t)((nt * 8 + kc) * 64 + lane)) * 8 + j;
    hi[fi] = h;
    lo[fi] = (_Float16)(w - (float)h);
}

__global__ __launch_bounds__(256, 3) void pinn_mfma(
    const float* __restrict__ x,
    const float* __restrict__ W1, const float* __restrict__ b1,
    const float* __restrict__ b2, const float* __restrict__ b3,
    const float* __restrict__ W4, const float* __restrict__ b4,
    const _Float16* __restrict__ wsf,
    float* __restrict__ out, int B)
{
    __shared__ __align__(16) _Float16 Ahi[3][TM][LDK];
    __shared__ __align__(16) _Float16 Alo[3][TM][LDK];
    __shared__ float psumW[4][3][TM];

    const int tid  = threadIdx.x;
    const int s0   = blockIdx.x * TM;
    const int lane = tid & 63;
    const int wave = tid >> 6;

    // ---------- Layer 1: thread owns sample m, 16 consecutive units ----------
    {
        const int m  = tid >> 4;
        const int k0 = (tid & 15) * 16;
        const float x0 = x[(s0 + m) * 2 + 0];
        const float x1 = x[(s0 + m) * 2 + 1];
        half8 vh[3][2], vl[3][2];
        #pragma unroll
        for (int hfi = 0; hfi < 2; ++hfi) {
            #pragma unroll
            for (int j = 0; j < 8; ++j) {
                const int n = k0 + hfi * 8 + j;
                const float w0 = W1[n];           // z1' = w0
                const float w1 = W1[HID + n];
                const float z  = fmaf(x0, w0, fmaf(x1, w1, b1[n]));
                const float a  = fast_tanh(z);
                const float sN = 1.0f - a * a;
                const float ad  = sN * w0;
                const float add = -2.0f * a * ad * w0;
                _Float16 h;
                h = (_Float16)a;   vh[0][hfi][j] = h; vl[0][hfi][j] = (_Float16)(a   - (float)h);
                h = (_Float16)ad;  vh[1][hfi][j] = h; vl[1][hfi][j] = (_Float16)(ad  - (float)h);
                h = (_Float16)add; vh[2][hfi][j] = h; vl[2][hfi][j] = (_Float16)(add - (float)h);
            }
        }
        #pragma unroll
        for (int s = 0; s < 3; ++s) {
            *(half8*)&Ahi[s][m][k0]     = vh[s][0];
            *(half8*)&Ahi[s][m][k0 + 8] = vh[s][1];
            *(half8*)&Alo[s][m][k0]     = vl[s][0];
            *(half8*)&Alo[s][m][k0 + 8] = vl[s][1];
        }
    }
    __syncthreads();

    const int ml = lane & 15;            // B-frag col = sample
    const int kq = (lane >> 4) * 8;      // frag k offset within 32-chunk
    const int u4 = (lane >> 4) * 4;      // D-row sub-offset (unit)

    // ---------- Layers 2 and 3 ----------
    #pragma unroll 1
    for (int layer = 0; layer < 2; ++layer) {
        const _Float16* __restrict__ Wh = wsf + (size_t)layer * 131072;
        const _Float16* __restrict__ Wl = Wh + 65536;

        f32x4 acc[3][4];
        #pragma unroll
        for (int s = 0; s < 3; ++s)
            #pragma unroll
            for (int nt = 0; nt < 4; ++nt)
                acc[s][nt] = (f32x4){0.f, 0.f, 0.f, 0.f};

        #pragma unroll 1
        for (int kc = 0; kc < 8; ++kc) {
            half8 wh[4], wl[4], ah[3], al[3];
            #pragma unroll
            for (int nt = 0; nt < 4; ++nt) {
                const size_t fi = ((size_t)(((wave * 4 + nt) * 8 + kc) * 64 + lane)) * 8;
                wh[nt] = *(const half8*)&Wh[fi];
                wl[nt] = *(const half8*)&Wl[fi];
            }
            #pragma unroll
            for (int s = 0; s < 3; ++s) {
                ah[s] = *(const half8*)&Ahi[s][ml][kc * 32 + kq];
                al[s] = *(const half8*)&Alo[s][ml][kc * 32 + kq];
            }
            #pragma unroll
            for (int s = 0; s < 3; ++s) {
                #pragma unroll
                for (int nt = 0; nt < 4; ++nt) {
                    acc[s][nt] = __builtin_amdgcn_mfma_f32_16x16x32_f16(wh[nt], ah[s], acc[s][nt], 0, 0, 0);
                    acc[s][nt] = __builtin_amdgcn_mfma_f32_16x16x32_f16(wh[nt], al[s], acc[s][nt], 0, 0, 0);
                    acc[s][nt] = __builtin_amdgcn_mfma_f32_16x16x32_f16(wl[nt], ah[s], acc[s][nt], 0, 0, 0);
                }
            }
        }

        __syncthreads();   // all waves done reading A before overwrite / reuse

        if (layer == 0) {
            // ----- layer-2 epilogue: tanh chain, split, vectorized LDS write -----
            #pragma unroll
            for (int nt = 0; nt < 4; ++nt) {
                const int ub = wave * 64 + nt * 16 + u4;     // 4 consecutive units
                const f32x4 bb = *(const f32x4*)&b2[ub];
                half4 hv[3], lv[3];
                #pragma unroll
                for (int r = 0; r < 4; ++r) {
                    const float z   = acc[0][nt][r] + bb[r];
                    const float a   = fast_tanh(z);
                    const float sN  = 1.0f - a * a;
                    const float zd  = acc[1][nt][r];
                    const float zdd = acc[2][nt][r];
                    const float ad  = sN * zd;
                    const float add = fmaf(sN, zdd, -2.0f * a * ad * zd);
                    _Float16 h;
                    h = (_Float16)a;   hv[0][r] = h; lv[0][r] = (_Float16)(a   - (float)h);
                    h = (_Float16)ad;  hv[1][r] = h; lv[1][r] = (_Float16)(ad  - (float)h);
                    h = (_Float16)add; hv[2][r] = h; lv[2][r] = (_Float16)(add - (float)h);
                }
                #pragma unroll
                for (int s = 0; s < 3; ++s) {
                    *(half4*)&Ahi[s][ml][ub] = hv[s];
                    *(half4*)&Alo[s][ml][ub] = lv[s];
                }
            }
            __syncthreads();
        } else {
            // ----- layer-3 epilogue fused with W4 dot: all in registers -----
            float pd0 = 0.f, pd1 = 0.f, pd2 = 0.f;
            #pragma unroll
            for (int nt = 0; nt < 4; ++nt) {
                const int ub = wave * 64 + nt * 16 + u4;
                const f32x4 bb = *(const f32x4*)&b3[ub];
                const f32x4 w4 = *(const f32x4*)&W4[ub];
                #pragma unroll
                for (int r = 0; r < 4; ++r) {
                    const float z   = acc[0][nt][r] + bb[r];
                    const float a   = fast_tanh(z);
                    const float sN  = 1.0f - a * a;
                    const float zd  = acc[1][nt][r];
                    const float zdd = acc[2][nt][r];
                    const float ad  = sN * zd;
                    const float add = fmaf(sN, zdd, -2.0f * a * ad * zd);
                    pd0 = fmaf(a,   w4[r], pd0);
                    pd1 = fmaf(ad,  w4[r], pd1);
                    pd2 = fmaf(add, w4[r], pd2);
                }
            }
            // butterfly over lanes {m, m+16, m+32, m+48}
            pd0 += __shfl_xor(pd0, 16, 64); pd0 += __shfl_xor(pd0, 32, 64);
            pd1 += __shfl_xor(pd1, 16, 64); pd1 += __shfl_xor(pd1, 32, 64);
            pd2 += __shfl_xor(pd2, 16, 64); pd2 += __shfl_xor(pd2, 32, 64);
            if (lane < 16) {
                psumW[wave][0][lane] = pd0;
                psumW[wave][1][lane] = pd1;
                psumW[wave][2][lane] = pd2;
            }
        }
    }
    __syncthreads();

    if (tid < 48) {
        const int s = tid >> 4;          // 0:u 1:du 2:d2u
        const int m = tid & 15;
        float v = psumW[0][s][m] + psumW[1][s][m] + psumW[2][s][m] + psumW[3][s][m];
        if (s == 0) v += b4[0];
        out[(size_t)s * B + s0 + m] = v;
    }
}

extern "C" void kernel_launch(void* const* d_in, const int* in_sizes, int n_in,
                              void* d_out, int out_size, void* d_ws, size_t ws_size,
                              hipStream_t stream) {
    const float* x  = (const float*)d_in[0];
    const float* W1 = (const float*)d_in[1];
    const float* b1 = (const float*)d_in[2];
    const float* W2 = (const float*)d_in[3];
    const float* b2 = (const float*)d_in[4];
    const float* W3 = (const float*)d_in[5];
    const float* b3 = (const float*)d_in[6];
    const float* W4 = (const float*)d_in[7];
    const float* b4 = (const float*)d_in[8];
    float* out = (float*)d_out;

    const int B = in_sizes[0] / 2;      // x is (B, 2)

    prep_w<<<512, 256, 0, stream>>>(W2, W3, (_Float16*)d_ws);
    pinn_mfma<<<B / TM, 256, 0, stream>>>(x, W1, b1, b2, b3, W4, b4,
                                          (const _Float16*)d_ws, out, B);
}

// Round 4
// 316.991 us; speedup vs baseline: 3.9388x; 1.0426x over previous
//
#include <hip/hip_runtime.h>

// PINN fused: u, du/dx0, d2u/dx0^2 of tanh-MLP (2->256->256->256->1), fp32 in/out.
// Round 4: reduced-split fp16 MFMA.
//   Activations quantized to fp16 (hi only) -> single LDS array, 3 ds_reads/kc.
//   Weights: value stream uses 2-term split (wh+wl, exact to 2^-22);
//            tangent streams use wh only (random-walk error ~1e-4 rel over K=256).
//   16 MFMAs per k-chunk (was 36). LDS 25.5KB -> 6 blocks/CU for phase overlap.

#define HID 256
#define TM  16
#define LDK 264   // padded LDS row stride in f16 elems

typedef _Float16 half8 __attribute__((ext_vector_type(8)));
typedef _Float16 half4 __attribute__((ext_vector_type(4)));
typedef float    f32x4 __attribute__((ext_vector_type(4)));

__device__ __forceinline__ float fast_tanh(float z) {
    // tanh(z) = 1 - 2/(exp(2z)+1); saturates correctly at +-inf
    const float e = __expf(2.0f * z);
#if __has_builtin(__builtin_amdgcn_rcpf)
    const float r = __builtin_amdgcn_rcpf(e + 1.0f);
#else
    const float r = 1.0f / (e + 1.0f);
#endif
    return fmaf(-2.0f, r, 1.0f);
}

// Pack W2/W3 (fp32 [256][256], row=k, col=n) into MFMA A-fragment order for W^T:
// frag (nt, kc, lane, j) = W[kc*32 + (lane>>4)*8 + j][nt*16 + (lane&15)]
// hi = fp16(w), lo = fp16(w - hi).  ws layout (f16): W2hi@0, W2lo@65536, W3hi@131072, W3lo@196608.
// Vectorized: one thread -> one 8-elem frag row, b128 stores.
__global__ __launch_bounds__(256) void prep_w(const float* __restrict__ W2,
                                              const float* __restrict__ W3,
                                              _Float16* __restrict__ wsf) {
    const int t = blockIdx.x * 256 + threadIdx.x;     // 0..16383
    const float* __restrict__ W = (t >> 13) ? W3 : W2;
    _Float16* hi = wsf + (size_t)(t >> 13) * 131072;
    _Float16* lo = hi + 65536;
    const int r    = t & 8191;
    const int nt   = r >> 9;
    const int kc   = (r >> 6) & 7;
    const int lane = r & 63;
    const int row  = kc * 32 + ((lane >> 4) << 3);
    const int col  = nt * 16 + (lane & 15);
    half8 vh, vl;
    #pragma unroll
    for (int j = 0; j < 8; ++j) {
        const float w = W[(size_t)(row + j) * HID + col];
        const _Float16 h = (_Float16)w;
        vh[j] = h;
        vl[j] = (_Float16)(w - (float)h);
    }
    *(half8*)&hi[(size_t)r * 8] = vh;
    *(half8*)&lo[(size_t)r * 8] = vl;
}

__global__ __launch_bounds__(256, 6) void pinn_mfma(
    const float* __restrict__ x,
    const float* __restrict__ W1, const float* __restrict__ b1,
    const float* __restrict__ b2, const float* __restrict__ b3,
    const float* __restrict__ W4, const float* __restrict__ b4,
    const _Float16* __restrict__ wsf,
    float* __restrict__ out, int B)
{
    __shared__ __align__(16) _Float16 Ahi[3][TM][LDK];
    __shared__ float psumW[4][3][TM];

    const int tid  = threadIdx.x;
    const int s0   = blockIdx.x * TM;
    const int lane = tid & 63;
    const int wave = tid >> 6;

    // ---------- Layer 1: thread owns sample m, 16 consecutive units ----------
    {
        const int m  = tid >> 4;
        const int k0 = (tid & 15) * 16;
        const float x0 = x[(s0 + m) * 2 + 0];
        const float x1 = x[(s0 + m) * 2 + 1];
        half8 vh[3][2];
        #pragma unroll
        for (int hfi = 0; hfi < 2; ++hfi) {
            #pragma unroll
            for (int j = 0; j < 8; ++j) {
                const int n = k0 + hfi * 8 + j;
                const float w0 = W1[n];           // z1' = w0
                const float w1 = W1[HID + n];
                const float z  = fmaf(x0, w0, fmaf(x1, w1, b1[n]));
                const float a  = fast_tanh(z);
                const float sN = 1.0f - a * a;
                const float ad  = sN * w0;
                const float add = -2.0f * a * ad * w0;
                vh[0][hfi][j] = (_Float16)a;
                vh[1][hfi][j] = (_Float16)ad;
                vh[2][hfi][j] = (_Float16)add;
            }
        }
        #pragma unroll
        for (int s = 0; s < 3; ++s) {
            *(half8*)&Ahi[s][m][k0]     = vh[s][0];
            *(half8*)&Ahi[s][m][k0 + 8] = vh[s][1];
        }
    }
    __syncthreads();

    const int ml = lane & 15;            // B-frag col = sample
    const int kq = (lane >> 4) * 8;      // frag k offset within 32-chunk
    const int u4 = (lane >> 4) * 4;      // D-row sub-offset (unit)

    // ---------- Layers 2 and 3 ----------
    #pragma unroll 1
    for (int layer = 0; layer < 2; ++layer) {
        const _Float16* __restrict__ Wh = wsf + (size_t)layer * 131072;
        const _Float16* __restrict__ Wl = Wh + 65536;

        f32x4 acc[3][4];
        #pragma unroll
        for (int s = 0; s < 3; ++s)
            #pragma unroll
            for (int nt = 0; nt < 4; ++nt)
                acc[s][nt] = (f32x4){0.f, 0.f, 0.f, 0.f};

        #pragma unroll 1
        for (int kc = 0; kc < 8; ++kc) {
            half8 ah[3];
            #pragma unroll
            for (int s = 0; s < 3; ++s)
                ah[s] = *(const half8*)&Ahi[s][ml][kc * 32 + kq];
            #pragma unroll
            for (int nt = 0; nt < 4; ++nt) {
                const size_t fi = ((size_t)(((wave * 4 + nt) * 8 + kc) * 64 + lane)) * 8;
                const half8 wh = *(const half8*)&Wh[fi];
                const half8 wl = *(const half8*)&Wl[fi];
                acc[0][nt] = __builtin_amdgcn_mfma_f32_16x16x32_f16(wh, ah[0], acc[0][nt], 0, 0, 0);
                acc[0][nt] = __builtin_amdgcn_mfma_f32_16x16x32_f16(wl, ah[0], acc[0][nt], 0, 0, 0);
                acc[1][nt] = __builtin_amdgcn_mfma_f32_16x16x32_f16(wh, ah[1], acc[1][nt], 0, 0, 0);
                acc[2][nt] = __builtin_amdgcn_mfma_f32_16x16x32_f16(wh, ah[2], acc[2][nt], 0, 0, 0);
            }
        }

        __syncthreads();   // all waves done reading A before overwrite / reuse

        if (layer == 0) {
            // ----- layer-2 epilogue: tanh chain, quantize hi, vectorized LDS write -----
            #pragma unroll
            for (int nt = 0; nt < 4; ++nt) {
                const int ub = wave * 64 + nt * 16 + u4;     // 4 consecutive units
                const f32x4 bb = *(const f32x4*)&b2[ub];
                half4 hv[3];
                #pragma unroll
                for (int r = 0; r < 4; ++r) {
                    const float z   = acc[0][nt][r] + bb[r];
                    const float a   = fast_tanh(z);
                    const float sN  = 1.0f - a * a;
                    const float zd  = acc[1][nt][r];
                    const float zdd = acc[2][nt][r];
                    const float ad  = sN * zd;
                    const float add = fmaf(sN, zdd, -2.0f * a * ad * zd);
                    hv[0][r] = (_Float16)a;
                    hv[1][r] = (_Float16)ad;
                    hv[2][r] = (_Float16)add;
                }
                #pragma unroll
                for (int s = 0; s < 3; ++s)
                    *(half4*)&Ahi[s][ml][ub] = hv[s];
            }
            __syncthreads();
        } else {
            // ----- layer-3 epilogue fused with W4 dot: all in registers (fp32) -----
            float pd0 = 0.f, pd1 = 0.f, pd2 = 0.f;
            #pragma unroll
            for (int nt = 0; nt < 4; ++nt) {
                const int ub = wave * 64 + nt * 16 + u4;
                const f32x4 bb = *(const f32x4*)&b3[ub];
                const f32x4 w4 = *(const f32x4*)&W4[ub];
                #pragma unroll
                for (int r = 0; r < 4; ++r) {
                    const float z   = acc[0][nt][r] + bb[r];
                    const float a   = fast_tanh(z);
                    const float sN  = 1.0f - a * a;
                    const float zd  = acc[1][nt][r];
                    const float zdd = acc[2][nt][r];
                    const float ad  = sN * zd;
                    const float add = fmaf(sN, zdd, -2.0f * a * ad * zd);
                    pd0 = fmaf(a,   w4[r], pd0);
                    pd1 = fmaf(ad,  w4[r], pd1);
                    pd2 = fmaf(add, w4[r], pd2);
                }
            }
            // butterfly over lanes {m, m+16, m+32, m+48}
            pd0 += __shfl_xor(pd0, 16, 64); pd0 += __shfl_xor(pd0, 32, 64);
            pd1 += __shfl_xor(pd1, 16, 64); pd1 += __shfl_xor(pd1, 32, 64);
            pd2 += __shfl_xor(pd2, 16, 64); pd2 += __shfl_xor(pd2, 32, 64);
            if (lane < 16) {
                psumW[wave][0][lane] = pd0;
                psumW[wave][1][lane] = pd1;
                psumW[wave][2][lane] = pd2;
            }
        }
    }
    __syncthreads();

    if (tid < 48) {
        const int s = tid >> 4;          // 0:u 1:du 2:d2u
        const int m = tid & 15;
        float v = psumW[0][s][m] + psumW[1][s][m] + psumW[2][s][m] + psumW[3][s][m];
        if (s == 0) v += b4[0];
        out[(size_t)s * B + s0 + m] = v;
    }
}

extern "C" void kernel_launch(void* const* d_in, const int* in_sizes, int n_in,
                              void* d_out, int out_size, void* d_ws, size_t ws_size,
                              hipStream_t stream) {
    const float* x  = (const float*)d_in[0];
    const float* W1 = (const float*)d_in[1];
    const float* b1 = (const float*)d_in[2];
    const float* W2 = (const float*)d_in[3];
    const float* b2 = (const float*)d_in[4];
    const float* W3 = (const float*)d_in[5];
    const float* b3 = (const float*)d_in[6];
    const float* W4 = (const float*)d_in[7];
    const float* b4 = (const float*)d_in[8];
    float* out = (float*)d_out;

    const int B = in_sizes[0] / 2;      // x is (B, 2)

    prep_w<<<64, 256, 0, stream>>>(W2, W3, (_Float16*)d_ws);
    pinn_mfma<<<B / TM, 256, 0, stream>>>(x, W1, b1, b2, b3, W4, b4,
                                          (const _Float16*)d_ws, out, B);
}

// Round 5
// 258.875 us; speedup vs baseline: 4.8230x; 1.2245x over previous
//
#include <hip/hip_runtime.h>

// PINN fused: u, du/dx0, d2u/dx0^2 of tanh-MLP (2->256->256->256->1), fp32 in/out.
// Round 5: round-4 structure with the spill fixed.
//   __launch_bounds__(256,4): VGPR cap 128 (acc 48 + frags + addr fits, no spill),
//   4 blocks/CU (LDS 26KB would allow 6, VGPR limits to 4). Round 4's (256,6)
//   capped VGPRs at 85 -> accumulator spill -> 290MB/dispatch scratch traffic.
//   Activations fp16 hi-only; weights 2-term split on value stream, hi-only on
//   tangent streams; 16 MFMAs per k-chunk.

#define HID 256
#define TM  16
#define LDK 264   // padded LDS row stride in f16 elems

typedef _Float16 half8 __attribute__((ext_vector_type(8)));
typedef _Float16 half4 __attribute__((ext_vector_type(4)));
typedef float    f32x4 __attribute__((ext_vector_type(4)));

__device__ __forceinline__ float fast_tanh(float z) {
    // tanh(z) = 1 - 2/(exp(2z)+1); saturates correctly at +-inf
    const float e = __expf(2.0f * z);
#if __has_builtin(__builtin_amdgcn_rcpf)
    const float r = __builtin_amdgcn_rcpf(e + 1.0f);
#else
    const float r = 1.0f / (e + 1.0f);
#endif
    return fmaf(-2.0f, r, 1.0f);
}

// Pack W2/W3 (fp32 [256][256], row=k, col=n) into MFMA A-fragment order for W^T:
// frag (nt, kc, lane, j) = W[kc*32 + (lane>>4)*8 + j][nt*16 + (lane&15)]
// hi = fp16(w), lo = fp16(w - hi).  ws layout (f16): W2hi@0, W2lo@65536, W3hi@131072, W3lo@196608.
__global__ __launch_bounds__(256) void prep_w(const float* __restrict__ W2,
                                              const float* __restrict__ W3,
                                              _Float16* __restrict__ wsf) {
    const int t = blockIdx.x * 256 + threadIdx.x;     // 0..16383
    const float* __restrict__ W = (t >> 13) ? W3 : W2;
    _Float16* hi = wsf + (size_t)(t >> 13) * 131072;
    _Float16* lo = hi + 65536;
    const int r    = t & 8191;
    const int nt   = r >> 9;
    const int kc   = (r >> 6) & 7;
    const int lane = r & 63;
    const int row  = kc * 32 + ((lane >> 4) << 3);
    const int col  = nt * 16 + (lane & 15);
    half8 vh, vl;
    #pragma unroll
    for (int j = 0; j < 8; ++j) {
        const float w = W[(size_t)(row + j) * HID + col];
        const _Float16 h = (_Float16)w;
        vh[j] = h;
        vl[j] = (_Float16)(w - (float)h);
    }
    *(half8*)&hi[(size_t)r * 8] = vh;
    *(half8*)&lo[(size_t)r * 8] = vl;
}

__global__ __launch_bounds__(256, 4) void pinn_mfma(
    const float* __restrict__ x,
    const float* __restrict__ W1, const float* __restrict__ b1,
    const float* __restrict__ b2, const float* __restrict__ b3,
    const float* __restrict__ W4, const float* __restrict__ b4,
    const _Float16* __restrict__ wsf,
    float* __restrict__ out, int B)
{
    __shared__ __align__(16) _Float16 Ahi[3][TM][LDK];
    __shared__ float psumW[4][3][TM];

    const int tid  = threadIdx.x;
    const int s0   = blockIdx.x * TM;
    const int lane = tid & 63;
    const int wave = tid >> 6;

    // ---------- Layer 1: thread owns sample m, 16 consecutive units ----------
    {
        const int m  = tid >> 4;
        const int k0 = (tid & 15) * 16;
        const float x0 = x[(s0 + m) * 2 + 0];
        const float x1 = x[(s0 + m) * 2 + 1];
        half8 vh[3][2];
        #pragma unroll
        for (int hfi = 0; hfi < 2; ++hfi) {
            #pragma unroll
            for (int j = 0; j < 8; ++j) {
                const int n = k0 + hfi * 8 + j;
                const float w0 = W1[n];           // z1' = w0
                const float w1 = W1[HID + n];
                const float z  = fmaf(x0, w0, fmaf(x1, w1, b1[n]));
                const float a  = fast_tanh(z);
                const float sN = 1.0f - a * a;
                const float ad  = sN * w0;
                const float add = -2.0f * a * ad * w0;
                vh[0][hfi][j] = (_Float16)a;
                vh[1][hfi][j] = (_Float16)ad;
                vh[2][hfi][j] = (_Float16)add;
            }
        }
        #pragma unroll
        for (int s = 0; s < 3; ++s) {
            *(half8*)&Ahi[s][m][k0]     = vh[s][0];
            *(half8*)&Ahi[s][m][k0 + 8] = vh[s][1];
        }
    }
    __syncthreads();

    const int ml = lane & 15;            // B-frag col = sample
    const int kq = (lane >> 4) * 8;      // frag k offset within 32-chunk
    const int u4 = (lane >> 4) * 4;      // D-row sub-offset (unit)

    // ---------- Layers 2 and 3 ----------
    #pragma unroll 1
    for (int layer = 0; layer < 2; ++layer) {
        const _Float16* __restrict__ Wh = wsf + (size_t)layer * 131072;
        const _Float16* __restrict__ Wl = Wh + 65536;

        f32x4 acc[3][4];
        #pragma unroll
        for (int s = 0; s < 3; ++s)
            #pragma unroll
            for (int nt = 0; nt < 4; ++nt)
                acc[s][nt] = (f32x4){0.f, 0.f, 0.f, 0.f};

        #pragma unroll 1
        for (int kc = 0; kc < 8; ++kc) {
            half8 ah[3];
            #pragma unroll
            for (int s = 0; s < 3; ++s)
                ah[s] = *(const half8*)&Ahi[s][ml][kc * 32 + kq];
            #pragma unroll
            for (int nt = 0; nt < 4; ++nt) {
                const size_t fi = ((size_t)(((wave * 4 + nt) * 8 + kc) * 64 + lane)) * 8;
                const half8 wh = *(const half8*)&Wh[fi];
                const half8 wl = *(const half8*)&Wl[fi];
                acc[0][nt] = __builtin_amdgcn_mfma_f32_16x16x32_f16(wh, ah[0], acc[0][nt], 0, 0, 0);
                acc[0][nt] = __builtin_amdgcn_mfma_f32_16x16x32_f16(wl, ah[0], acc[0][nt], 0, 0, 0);
                acc[1][nt] = __builtin_amdgcn_mfma_f32_16x16x32_f16(wh, ah[1], acc[1][nt], 0, 0, 0);
                acc[2][nt] = __builtin_amdgcn_mfma_f32_16x16x32_f16(wh, ah[2], acc[2][nt], 0, 0, 0);
            }
        }

        __syncthreads();   // all waves done reading A before overwrite / reuse

        if (layer == 0) {
            // ----- layer-2 epilogue: tanh chain, quantize hi, vectorized LDS write -----
            #pragma unroll
            for (int nt = 0; nt < 4; ++nt) {
                const int ub = wave * 64 + nt * 16 + u4;     // 4 consecutive units
                const f32x4 bb = *(const f32x4*)&b2[ub];
                half4 hv[3];
                #pragma unroll
                for (int r = 0; r < 4; ++r) {
                    const float z   = acc[0][nt][r] + bb[r];
                    const float a   = fast_tanh(z);
                    const float sN  = 1.0f - a * a;
                    const float zd  = acc[1][nt][r];
                    const float zdd = acc[2][nt][r];
                    const float ad  = sN * zd;
                    const float add = fmaf(sN, zdd, -2.0f * a * ad * zd);
                    hv[0][r] = (_Float16)a;
                    hv[1][r] = (_Float16)ad;
                    hv[2][r] = (_Float16)add;
                }
                #pragma unroll
                for (int s = 0; s < 3; ++s)
                    *(half4*)&Ahi[s][ml][ub] = hv[s];
            }
            __syncthreads();
        } else {
            // ----- layer-3 epilogue fused with W4 dot: all in registers (fp32) -----
            float pd0 = 0.f, pd1 = 0.f, pd2 = 0.f;
            #pragma unroll
            for (int nt = 0; nt < 4; ++nt) {
                const int ub = wave * 64 + nt * 16 + u4;
                const f32x4 bb = *(const f32x4*)&b3[ub];
                const f32x4 w4 = *(const f32x4*)&W4[ub];
                #pragma unroll
                for (int r = 0; r < 4; ++r) {
                    const float z   = acc[0][nt][r] + bb[r];
                    const float a   = fast_tanh(z);
                    const float sN  = 1.0f - a * a;
                    const float zd  = acc[1][nt][r];
                    const float zdd = acc[2][nt][r];
                    const float ad  = sN * zd;
                    const float add = fmaf(sN, zdd, -2.0f * a * ad * zd);
                    pd0 = fmaf(a,   w4[r], pd0);
                    pd1 = fmaf(ad,  w4[r], pd1);
                    pd2 = fmaf(add, w4[r], pd2);
                }
            }
            // butterfly over lanes {m, m+16, m+32, m+48}
            pd0 += __shfl_xor(pd0, 16, 64); pd0 += __shfl_xor(pd0, 32, 64);
            pd1 += __shfl_xor(pd1, 16, 64); pd1 += __shfl_xor(pd1, 32, 64);
            pd2 += __shfl_xor(pd2, 16, 64); pd2 += __shfl_xor(pd2, 32, 64);
            if (lane < 16) {
                psumW[wave][0][lane] = pd0;
                psumW[wave][1][lane] = pd1;
                psumW[wave][2][lane] = pd2;
            }
        }
    }
    __syncthreads();

    if (tid < 48) {
        const int s = tid >> 4;          // 0:u 1:du 2:d2u
        const int m = tid & 15;
        float v = psumW[0][s][m] + psumW[1][s][m] + psumW[2][s][m] + psumW[3][s][m];
        if (s == 0) v += b4[0];
        out[(size_t)s * B + s0 + m] = v;
    }
}

extern "C" void kernel_launch(void* const* d_in, const int* in_sizes, int n_in,
                              void* d_out, int out_size, void* d_ws, size_t ws_size,
                              hipStream_t stream) {
    const float* x  = (const float*)d_in[0];
    const float* W1 = (const float*)d_in[1];
    const float* b1 = (const float*)d_in[2];
    const float* W2 = (const float*)d_in[3];
    const float* b2 = (const float*)d_in[4];
    const float* W3 = (const float*)d_in[5];
    const float* b3 = (const float*)d_in[6];
    const float* W4 = (const float*)d_in[7];
    const float* b4 = (const float*)d_in[8];
    float* out = (float*)d_out;

    const int B = in_sizes[0] / 2;      // x is (B, 2)

    prep_w<<<64, 256, 0, stream>>>(W2, W3, (_Float16*)d_ws);
    pinn_mfma<<<B / TM, 256, 0, stream>>>(x, W1, b1, b2, b3, W4, b4,
                                          (const _Float16*)d_ws, out, B);
}

// Round 6
// 189.312 us; speedup vs baseline: 6.5952x; 1.3675x over previous
//
#include <hip/hip_runtime.h>

// PINN fused: u, du/dx0, d2u/dx0^2 of tanh-MLP (2->256->256->256->1), fp32 in/out.
// Round 6: attack L2 weight bandwidth (the round-5 binding pipe: 4.3GB L2
// reads/dispatch = 116us at L2 peak vs 66us MFMA floor).
//   - TM=32 samples/block (512 thr, 8 waves, wave = 32 units x 32 samples):
//     halves weight re-reads.
//   - hi-only fp16 weights (absmax floor is harness-side 2^-8, identical since
//     the fp32 round; fp16 weight quant adds ~1e-4): halves packed bytes again
//     and cuts MFMAs/kc 16->12.  L2 traffic 4.3GB -> 1.07GB; floor 66->50us.
//   - __launch_bounds__(512,4): VGPR cap 128, est ~105 live, no spill
//     (round-4 lesson: cap 85 vs need 110 spilled to scratch).

#define HID 256
#define TM  32
#define LDK 264   // padded LDS row stride in f16 elems

typedef _Float16 half8 __attribute__((ext_vector_type(8)));
typedef _Float16 half4 __attribute__((ext_vector_type(4)));
typedef float    f32x4 __attribute__((ext_vector_type(4)));

__device__ __forceinline__ float fast_tanh(float z) {
    // tanh(z) = 1 - 2/(exp(2z)+1); saturates correctly at +-inf
    const float e = __expf(2.0f * z);
#if __has_builtin(__builtin_amdgcn_rcpf)
    const float r = __builtin_amdgcn_rcpf(e + 1.0f);
#else
    const float r = 1.0f / (e + 1.0f);
#endif
    return fmaf(-2.0f, r, 1.0f);
}

// Pack W2/W3 (fp32 [256][256], row=k, col=n) into MFMA A-fragment order for W^T,
// fp16 hi only: frag (strip nt, kc, lane, j) = W[kc*32+(lane>>4)*8+j][nt*16+(lane&15)]
// ws layout (f16 elems): W2 @ 0, W3 @ 65536.  (256KB total)
__global__ __launch_bounds__(256) void prep_w(const float* __restrict__ W2,
                                              const float* __restrict__ W3,
                                              _Float16* __restrict__ wsf) {
    const int t = blockIdx.x * 256 + threadIdx.x;     // 0..16383
    const float* __restrict__ W = (t >> 13) ? W3 : W2;
    _Float16* hi = wsf + (size_t)(t >> 13) * 65536;
    const int r    = t & 8191;
    const int nt   = r >> 9;
    const int kc   = (r >> 6) & 7;
    const int lane = r & 63;
    const int row  = kc * 32 + ((lane >> 4) << 3);
    const int col  = nt * 16 + (lane & 15);
    half8 vh;
    #pragma unroll
    for (int j = 0; j < 8; ++j)
        vh[j] = (_Float16)W[(size_t)(row + j) * HID + col];
    *(half8*)&hi[(size_t)r * 8] = vh;
}

__global__ __launch_bounds__(512, 4) void pinn_mfma(
    const float* __restrict__ x,
    const float* __restrict__ W1, const float* __restrict__ b1,
    const float* __restrict__ b2, const float* __restrict__ b3,
    const float* __restrict__ W4, const float* __restrict__ b4,
    const _Float16* __restrict__ wsf,
    float* __restrict__ out, int B)
{
    __shared__ __align__(16) _Float16 Ahi[3][TM][LDK];
    __shared__ float psumW[8][3][TM];

    const int tid  = threadIdx.x;
    const int s0   = blockIdx.x * TM;
    const int lane = tid & 63;
    const int wave = tid >> 6;          // 0..7

    // ---------- Layer 1: thread owns sample m (0..31), 16 consecutive units ----------
    {
        const int m  = tid >> 4;
        const int k0 = (tid & 15) * 16;
        const float x0 = x[(s0 + m) * 2 + 0];
        const float x1 = x[(s0 + m) * 2 + 1];
        half8 vh[3][2];
        #pragma unroll
        for (int hfi = 0; hfi < 2; ++hfi) {
            #pragma unroll
            for (int j = 0; j < 8; ++j) {
                const int n = k0 + hfi * 8 + j;
                const float w0 = W1[n];           // z1' = w0
                const float w1 = W1[HID + n];
                const float z  = fmaf(x0, w0, fmaf(x1, w1, b1[n]));
                const float a  = fast_tanh(z);
                const float sN = 1.0f - a * a;
                const float ad  = sN * w0;
                const float add = -2.0f * a * ad * w0;
                vh[0][hfi][j] = (_Float16)a;
                vh[1][hfi][j] = (_Float16)ad;
                vh[2][hfi][j] = (_Float16)add;
            }
        }
        #pragma unroll
        for (int s = 0; s < 3; ++s) {
            *(half8*)&Ahi[s][m][k0]     = vh[s][0];
            *(half8*)&Ahi[s][m][k0 + 8] = vh[s][1];
        }
    }
    __syncthreads();

    const int ml = lane & 15;            // B-frag col = sample (within 16-tile)
    const int kq = (lane >> 4) * 8;      // frag k offset within 32-chunk
    const int u4 = (lane >> 4) * 4;      // D-row sub-offset (unit)

    // ---------- Layers 2 and 3 ----------
    #pragma unroll 1
    for (int layer = 0; layer < 2; ++layer) {
        const _Float16* __restrict__ Wh = wsf + (size_t)layer * 65536;

        f32x4 acc[3][2][2];              // [stream][nt][mt]
        #pragma unroll
        for (int s = 0; s < 3; ++s)
            #pragma unroll
            for (int nt = 0; nt < 2; ++nt)
                #pragma unroll
                for (int mt = 0; mt < 2; ++mt)
                    acc[s][nt][mt] = (f32x4){0.f, 0.f, 0.f, 0.f};

        #pragma unroll 1
        for (int kc = 0; kc < 8; ++kc) {
            half8 ah[3][2];              // [stream][mt]
            #pragma unroll
            for (int s = 0; s < 3; ++s)
                #pragma unroll
                for (int mt = 0; mt < 2; ++mt)
                    ah[s][mt] = *(const half8*)&Ahi[s][mt * 16 + ml][kc * 32 + kq];
            #pragma unroll
            for (int nt = 0; nt < 2; ++nt) {
                const int strip = wave * 2 + nt;          // 0..15
                const size_t fi = ((size_t)((strip * 8 + kc) * 64 + lane)) * 8;
                const half8 wh = *(const half8*)&Wh[fi];
                #pragma unroll
                for (int mt = 0; mt < 2; ++mt) {
                    acc[0][nt][mt] = __builtin_amdgcn_mfma_f32_16x16x32_f16(wh, ah[0][mt], acc[0][nt][mt], 0, 0, 0);
                    acc[1][nt][mt] = __builtin_amdgcn_mfma_f32_16x16x32_f16(wh, ah[1][mt], acc[1][nt][mt], 0, 0, 0);
                    acc[2][nt][mt] = __builtin_amdgcn_mfma_f32_16x16x32_f16(wh, ah[2][mt], acc[2][nt][mt], 0, 0, 0);
                }
            }
        }

        __syncthreads();   // all waves done reading A before overwrite / reuse

        if (layer == 0) {
            // ----- layer-2 epilogue: tanh chain, quantize fp16, vectorized LDS write -----
            #pragma unroll
            for (int nt = 0; nt < 2; ++nt) {
                const int ub = wave * 32 + nt * 16 + u4;     // 4 consecutive units
                const f32x4 bb = *(const f32x4*)&b2[ub];
                #pragma unroll
                for (int mt = 0; mt < 2; ++mt) {
                    half4 hv[3];
                    #pragma unroll
                    for (int r = 0; r < 4; ++r) {
                        const float z   = acc[0][nt][mt][r] + bb[r];
                        const float a   = fast_tanh(z);
                        const float sN  = 1.0f - a * a;
                        const float zd  = acc[1][nt][mt][r];
                        const float zdd = acc[2][nt][mt][r];
                        const float ad  = sN * zd;
                        const float add = fmaf(sN, zdd, -2.0f * a * ad * zd);
                        hv[0][r] = (_Float16)a;
                        hv[1][r] = (_Float16)ad;
                        hv[2][r] = (_Float16)add;
                    }
                    #pragma unroll
                    for (int s = 0; s < 3; ++s)
                        *(half4*)&Ahi[s][mt * 16 + ml][ub] = hv[s];
                }
            }
            __syncthreads();
        } else {
            // ----- layer-3 epilogue fused with W4 dot: all in registers (fp32) -----
            float pd[3][2] = {{0.f, 0.f}, {0.f, 0.f}, {0.f, 0.f}};
            #pragma unroll
            for (int nt = 0; nt < 2; ++nt) {
                const int ub = wave * 32 + nt * 16 + u4;
                const f32x4 bb = *(const f32x4*)&b3[ub];
                const f32x4 w4 = *(const f32x4*)&W4[ub];
                #pragma unroll
                for (int mt = 0; mt < 2; ++mt) {
                    #pragma unroll
                    for (int r = 0; r < 4; ++r) {
                        const float z   = acc[0][nt][mt][r] + bb[r];
                        const float a   = fast_tanh(z);
                        const float sN  = 1.0f - a * a;
                        const float zd  = acc[1][nt][mt][r];
                        const float zdd = acc[2][nt][mt][r];
                        const float ad  = sN * zd;
                        const float add = fmaf(sN, zdd, -2.0f * a * ad * zd);
                        pd[0][mt] = fmaf(a,   w4[r], pd[0][mt]);
                        pd[1][mt] = fmaf(ad,  w4[r], pd[1][mt]);
                        pd[2][mt] = fmaf(add, w4[r], pd[2][mt]);
                    }
                }
            }
            // butterfly over lanes {ml, ml+16, ml+32, ml+48}
            #pragma unroll
            for (int s = 0; s < 3; ++s)
                #pragma unroll
                for (int mt = 0; mt < 2; ++mt) {
                    pd[s][mt] += __shfl_xor(pd[s][mt], 16, 64);
                    pd[s][mt] += __shfl_xor(pd[s][mt], 32, 64);
                }
            if (lane < 16) {
                #pragma unroll
                for (int s = 0; s < 3; ++s) {
                    psumW[wave][s][lane]      = pd[s][0];
                    psumW[wave][s][16 + lane] = pd[s][1];
                }
            }
        }
    }
    __syncthreads();

    if (tid < 96) {
        const int s = tid >> 5;          // 0:u 1:du 2:d2u
        const int m = tid & 31;
        float v = 0.f;
        #pragma unroll
        for (int w = 0; w < 8; ++w) v += psumW[w][s][m];
        if (s == 0) v += b4[0];
        out[(size_t)s * B + s0 + m] = v;
    }
}

extern "C" void kernel_launch(void* const* d_in, const int* in_sizes, int n_in,
                              void* d_out, int out_size, void* d_ws, size_t ws_size,
                              hipStream_t stream) {
    const float* x  = (const float*)d_in[0];
    const float* W1 = (const float*)d_in[1];
    const float* b1 = (const float*)d_in[2];
    const float* W2 = (const float*)d_in[3];
    const float* b2 = (const float*)d_in[4];
    const float* W3 = (const float*)d_in[5];
    const float* b3 = (const float*)d_in[6];
    const float* W4 = (const float*)d_in[7];
    const float* b4 = (const float*)d_in[8];
    float* out = (float*)d_out;

    const int B = in_sizes[0] / 2;      // x is (B, 2)

    prep_w<<<64, 256, 0, stream>>>(W2, W3, (_Float16*)d_ws);
    pinn_mfma<<<B / TM, 512, 0, stream>>>(x, W1, b1, b2, b3, W4, b4,
                                          (const _Float16*)d_ws, out, B);
}